// Round 1
// 477.884 us; speedup vs baseline: 1.0505x; 1.0505x over previous
//
#include <hip/hip_runtime.h>

// Problem: hidden_states [B=8, T=2048, F=128, C=32] fp32, cumulative
// group-norm over time; stats reduced over (F,C).
//
// Single-pass fused kernel using decoupled-lookback prefix scan:
//   - one block per 4 consecutive timesteps (one "group", 64 KB in registers)
//   - chain A: cumulative sum of x  -> per-t mean
//   - chain B: cumulative sum of per-t squared deviation -> per-t var
//   - normalize from registers, write out. x read ONCE, out written ONCE.

#define B_DIM 8
#define T_DIM 2048
#define FC 4096
#define SPB 4                        // timesteps (slabs) per block
#define GPB (T_DIM / SPB)            // 512 chain entries per batch
#define NGRP (B_DIM * GPB)           // 4096 blocks / chain entries total
#define EPS 1e-3f

typedef unsigned long long u64;
typedef unsigned int u32;

// ws layout: chain entries pack {state:hi32 | f32 value:lo32} in one u64 so a
// single relaxed atomic load/store is self-consistent (no fences needed,
// works across XCDs at agent scope). state: 0=empty, 1=aggregate, 2=inclusive.
struct Chain {
  u64 a[NGRP];   // chain A: sum(x)
  u64 b[NGRP];   // chain B: sum((x-mean_t)^2) terms
  u32 ticket;
};

__global__ __launch_bounds__(256) void clear_kernel(Chain* __restrict__ ch) {
  const int i = blockIdx.x * 256 + threadIdx.x;
  if (i < NGRP) { ch->a[i] = 0ull; ch->b[i] = 0ull; }
  if (i == 0) ch->ticket = 0u;
}

__device__ __forceinline__ u64 pack_entry(u32 st, float v) {
  return ((u64)st << 32) | (u64)__float_as_uint(v);
}

// Lane-parallel decoupled lookback over entry[0..p): returns exclusive prefix
// (broadcast to all 64 lanes of the calling wave). Window of 64 entries per
// round; consumes aggregates until an inclusive short-circuits.
__device__ __forceinline__ float lookback(u64* __restrict__ entry, int p, int lane) {
  float pref = 0.f;
  int j = p - 1;
  while (j >= 0) {
    const int idx = j - lane;            // lane 0 = nearest predecessor
    const bool valid = idx >= 0;
    u64 e = valid ? __hip_atomic_load(&entry[idx], __ATOMIC_RELAXED,
                                      __HIP_MEMORY_SCOPE_AGENT)
                  : 0ull;
    const u32 st = (u32)(e >> 32);
    const u64 b2 = __ballot(valid && st == 2u);
    const u64 b0 = __ballot(valid && st == 0u);
    const int f2 = b2 ? (__ffsll(b2) - 1) : 64;  // nearest inclusive
    const int f0 = b0 ? (__ffsll(b0) - 1) : 64;  // nearest hole
    if (f0 < f2) {                       // hole before usable inclusive: spin
      __builtin_amdgcn_s_sleep(2);
      continue;
    }
    // lanes < f2 hold aggregates, lane f2 (if <64) holds the inclusive
    float c = (valid && lane <= f2) ? __uint_as_float((u32)e) : 0.f;
#pragma unroll
    for (int o = 32; o >= 1; o >>= 1) c += __shfl_xor(c, o, 64);
    pref += c;
    if (f2 < 64) break;                  // inclusive found: chain resolved
    j -= 64;
  }
  return pref;
}

__global__ __launch_bounds__(256, 4) void fused_kernel(
    const float* __restrict__ x, const float* __restrict__ scale,
    float* __restrict__ out, Chain* __restrict__ ch) {
  __shared__ u32 s_vbid;
  __shared__ float s_sq[4][8];    // per-wave partials: [wave][s0..3 | q0..3]
  __shared__ float s_slab[8];     // block totals:       s0..3 | q0..3
  __shared__ float2 s_mi[SPB];    // per-slab {mean, inv_std}

  const int tid = threadIdx.x;
  const int lane = tid & 63;
  const int wave = tid >> 6;

  // Ticket: virtual block id in dispatch order (deadlock-free lookback).
  if (tid == 0) s_vbid = atomicAdd(&ch->ticket, 1u);
  __syncthreads();
  const u32 vbid = s_vbid;
  const int batch = vbid >> 9;            // / GPB
  const int p = vbid & (GPB - 1);         // position in this batch's chain
  const int t0 = p * SPB;

  // ---- load 4 slabs (64 KB) into registers, per-slab partial sums ----
  const size_t base = (size_t)(batch * T_DIM + t0) * FC;
  const float4* px = (const float4*)(x + base);
  float4 v[SPB][4];
  float sj[SPB], qj[SPB];
#pragma unroll
  for (int j = 0; j < SPB; ++j) {
    float s = 0.f, q = 0.f;
#pragma unroll
    for (int k = 0; k < 4; ++k) {
      float4 t = px[j * 1024 + k * 256 + tid];   // wave-contiguous 1KB/instr
      v[j][k] = t;
      s += t.x + t.y + t.z + t.w;
      q += t.x * t.x + t.y * t.y + t.z * t.z + t.w * t.w;
    }
    sj[j] = s;
    qj[j] = q;
  }

  // ---- block reduction: per-slab {s,q} ----
#pragma unroll
  for (int j = 0; j < SPB; ++j) {
#pragma unroll
    for (int o = 32; o >= 1; o >>= 1) {
      sj[j] += __shfl_xor(sj[j], o, 64);
      qj[j] += __shfl_xor(qj[j], o, 64);
    }
  }
  if (lane == 0) {
#pragma unroll
    for (int j = 0; j < SPB; ++j) {
      s_sq[wave][j] = sj[j];
      s_sq[wave][4 + j] = qj[j];
    }
  }
  __syncthreads();
  if (tid < 8)
    s_slab[tid] = s_sq[0][tid] + s_sq[1][tid] + s_sq[2][tid] + s_sq[3][tid];
  __syncthreads();

  // ---- wave 0: resolve both chains, produce per-slab {mean, inv} ----
  if (wave == 0) {
    float S[SPB], Q[SPB];
#pragma unroll
    for (int j = 0; j < SPB; ++j) {
      S[j] = s_slab[j];
      Q[j] = s_slab[4 + j];
    }
    u64* eA = ch->a + batch * GPB;
    u64* eB = ch->b + batch * GPB;

    // chain A: cumulative sum of x
    const float aggS = S[0] + S[1] + S[2] + S[3];
    if (p > 0 && lane == 0)
      __hip_atomic_store(&eA[p], pack_entry(1u, aggS), __ATOMIC_RELAXED,
                         __HIP_MEMORY_SCOPE_AGENT);
    const float prefS = (p > 0) ? lookback(eA, p, lane) : 0.f;
    if (lane == 0)
      __hip_atomic_store(&eA[p], pack_entry(2u, prefS + aggS), __ATOMIC_RELAXED,
                         __HIP_MEMORY_SCOPE_AGENT);

    // per-t mean and squared-deviation term (same math as verified 3-kernel)
    float m[SPB], S2[SPB];
    float run = prefS;
#pragma unroll
    for (int j = 0; j < SPB; ++j) {
      run += S[j];
      const float cnt = (float)FC * (float)(t0 + j + 1);
      m[j] = run / cnt;
      S2[j] = Q[j] - 2.f * m[j] * S[j] + (float)FC * m[j] * m[j];
    }

    // chain B: cumulative sum of S2
    const float aggV = S2[0] + S2[1] + S2[2] + S2[3];
    if (p > 0 && lane == 0)
      __hip_atomic_store(&eB[p], pack_entry(1u, aggV), __ATOMIC_RELAXED,
                         __HIP_MEMORY_SCOPE_AGENT);
    const float prefV = (p > 0) ? lookback(eB, p, lane) : 0.f;
    if (lane == 0) {
      __hip_atomic_store(&eB[p], pack_entry(2u, prefV + aggV), __ATOMIC_RELAXED,
                         __HIP_MEMORY_SCOPE_AGENT);
      float r2 = prefV;
#pragma unroll
      for (int j = 0; j < SPB; ++j) {
        r2 += S2[j];
        const float cnt = (float)FC * (float)(t0 + j + 1);
        float2 mi;
        mi.x = m[j];
        mi.y = rsqrtf(r2 / cnt + EPS);
        s_mi[j] = mi;
      }
    }
  }
  __syncthreads();

  // ---- normalize from registers, store ----
  // element channel for this thread is (tid*4)&31 .. +3 for every k,j
  const float4 sc = *(const float4*)(scale + ((tid * 4) & 31));
  float4* po = (float4*)(out + base);
#pragma unroll
  for (int j = 0; j < SPB; ++j) {
    const float2 mi = s_mi[j];
#pragma unroll
    for (int k = 0; k < 4; ++k) {
      float4 t = v[j][k];
      float4 r;
      r.x = (t.x - mi.x) * mi.y * sc.x;
      r.y = (t.y - mi.x) * mi.y * sc.y;
      r.z = (t.z - mi.x) * mi.y * sc.z;
      r.w = (t.w - mi.x) * mi.y * sc.w;
      po[j * 1024 + k * 256 + tid] = r;
    }
  }
}

extern "C" void kernel_launch(void* const* d_in, const int* in_sizes, int n_in,
                              void* d_out, int out_size, void* d_ws, size_t ws_size,
                              hipStream_t stream) {
  const float* x = (const float*)d_in[0];
  const float* scale = (const float*)d_in[1];
  float* out = (float*)d_out;
  Chain* ch = (Chain*)d_ws;   // 64 KB + 4 B used

  clear_kernel<<<(NGRP + 255) / 256, 256, 0, stream>>>(ch);
  fused_kernel<<<NGRP, 256, 0, stream>>>(x, scale, out, ch);
}